// Round 2
// baseline (1049.089 us; speedup 1.0000x reference)
//
#include <hip/hip_runtime.h>
#include <hip/hip_bf16.h>

#define N_POINTS 100000
#define K_VOL 27
#define PAIRS 60000
#define CCH 64                       // C_IN == C_OUT == 64
#define E_TOT (K_VOL * PAIRS)        // 1,620,000 entries
#define TILES_PER_K (PAIRS / 16)     // fallback path
#define BX 64                        // fallback path
#define NWAVES 4                     // fallback path

#define RPB 128                                    // rows per output bucket
#define NBUCKETS ((N_POINTS + RPB - 1) / RPB)      // 782
#define NBINS (NBUCKETS * K_VOL)                   // 21114
#define LDS_STRIDE 68                              // f32 stride: 16B-aligned rows, spreads banks

// workspace layout (bytes)
#define WS_ENTRIES 0
#define WS_OFF (E_TOT * 4)
#define WS_CUR (WS_OFF + (NBINS + 1) * 4)
#define WS_INBF (((WS_CUR + NBINS * 4) + 15) & ~15)
#define WS_WT (WS_INBF + N_POINTS * CCH * 2)
#define WS_NEED (WS_WT + K_VOL * CCH * CCH * 2)    // ~19.7 MB

typedef __bf16 bf16x8 __attribute__((ext_vector_type(8)));
typedef __bf16 bf16x4 __attribute__((ext_vector_type(4)));
typedef float f32x4 __attribute__((ext_vector_type(4)));

// ============================ new path ============================

// input f32 -> bf16 rows; weight f32 [k][ci][co] -> bf16 transposed wt[k][co][ci];
// zero the bin counters (off + cur are contiguous).
__global__ __launch_bounds__(256) void prep_kernel(
    const float* __restrict__ input, const float* __restrict__ weight,
    unsigned char* __restrict__ ws) {
  int t = blockIdx.x * 256 + threadIdx.x;  // exactly N*CCH/4 = 1,600,000 threads
  {
    float4 v = ((const float4*)input)[t];
    bf16x4 o;
    o[0] = (__bf16)v.x; o[1] = (__bf16)v.y; o[2] = (__bf16)v.z; o[3] = (__bf16)v.w;
    *(bf16x4*)(ws + WS_INBF + (size_t)t * 8) = o;
  }
  if (t < K_VOL * CCH * CCH) {             // 110592
    int k = t >> 12;
    int r = t & 4095;
    int ci = r >> 6, co = r & 63;
    *(__bf16*)(ws + WS_WT + (size_t)(((k * 64 + co) << 6) + ci) * 2) =
        (__bf16)weight[t];
  }
  if (t < 2 * NBINS + 1) {
    ((unsigned int*)(ws + WS_OFF))[t] = 0u;
  }
}

__global__ __launch_bounds__(256) void hist_kernel(
    const int* __restrict__ out_map, unsigned char* __restrict__ ws) {
  int p = blockIdx.x * 256 + threadIdx.x;
  int k = blockIdx.y;
  if (p < PAIRS) {
    int om = out_map[k * PAIRS + p];
    int bin = (om >> 7) * K_VOL + k;
    atomicAdd((unsigned int*)(ws + WS_OFF) + bin, 1u);
  }
}

#define SCAN_T 1024
#define SCAN_CH ((NBINS + SCAN_T - 1) / SCAN_T)  // 21
__global__ __launch_bounds__(1024) void scan_kernel(unsigned char* __restrict__ ws) {
  __shared__ unsigned int part[SCAN_T];
  unsigned int* off = (unsigned int*)(ws + WS_OFF);
  unsigned int* cur = (unsigned int*)(ws + WS_CUR);
  int t = threadIdx.x;
  int base = t * SCAN_CH;
  unsigned int s = 0;
  for (int i = 0; i < SCAN_CH; ++i) {
    int idx = base + i;
    if (idx < NBINS) s += off[idx];
  }
  part[t] = s;
  __syncthreads();
  for (int d = 1; d < SCAN_T; d <<= 1) {
    unsigned int v = (t >= d) ? part[t - d] : 0u;
    __syncthreads();
    part[t] += v;
    __syncthreads();
  }
  unsigned int run = (t > 0) ? part[t - 1] : 0u;
  for (int i = 0; i < SCAN_CH; ++i) {
    int idx = base + i;
    if (idx < NBINS) {
      unsigned int c = off[idx];
      off[idx] = run;
      cur[idx] = run;
      run += c;
    }
  }
  if (t == SCAN_T - 1) off[NBINS] = run;  // == E_TOT
}

// counting-sort the (k,p) pairs into bin order; entry = in_row | out_local<<17
__global__ __launch_bounds__(256) void scatter_kernel(
    const int* __restrict__ in_map, const int* __restrict__ out_map,
    unsigned char* __restrict__ ws) {
  int p = blockIdx.x * 256 + threadIdx.x;
  int k = blockIdx.y;
  if (p >= PAIRS) return;
  int om = out_map[k * PAIRS + p];
  int im = in_map[k * PAIRS + p];
  int bin = (om >> 7) * K_VOL + k;
  unsigned int pos = atomicAdd((unsigned int*)(ws + WS_CUR) + bin, 1u);
  ((unsigned int*)(ws + WS_ENTRIES))[pos] =
      (unsigned int)im | ((unsigned int)(om & (RPB - 1)) << 17);
}

// one block per 128-row output bucket; LDS f32 accumulator; per-k MFMA tiles;
// ds_add_f32 scatter; single coalesced write per output row (+bias).
__global__ __launch_bounds__(256) void spconv_main_kernel(
    const float* __restrict__ bias, const unsigned char* __restrict__ ws,
    float* __restrict__ out) {
  __shared__ float accs[RPB * LDS_STRIDE];  // 34,816 B -> 4 blocks/CU
  const unsigned int* off = (const unsigned int*)(ws + WS_OFF);
  const unsigned int* entries = (const unsigned int*)(ws + WS_ENTRIES);
  const __bf16* inbf = (const __bf16*)(ws + WS_INBF);
  const __bf16* wt = (const __bf16*)(ws + WS_WT);

  const int b = blockIdx.x;
  const int tid = threadIdx.x;
  const int wave = tid >> 6, lane = tid & 63;
  const int col = lane & 15, quad = lane >> 4;

  for (int i = tid; i < RPB * LDS_STRIDE; i += 256) accs[i] = 0.f;
  __syncthreads();

  for (int kb = wave; kb < K_VOL; kb += 4) {
    const int bin = b * K_VOL + kb;
    const unsigned int s0 = off[bin], e0 = off[bin + 1];
    if (s0 == e0) continue;

    // B fragments from transposed bf16 weights: contiguous 16B loads
    bf16x8 bfrag[4][2];
#pragma unroll
    for (int nt = 0; nt < 4; ++nt) {
      const __bf16* wrow = wt + ((kb * 64 + nt * 16 + col) << 6);
#pragma unroll
      for (int s = 0; s < 2; ++s)
        bfrag[nt][s] = *(const bf16x8*)(wrow + s * 32 + quad * 8);
    }

    for (unsigned int tb = s0; tb < e0; tb += 16) {
      unsigned int idx = tb + col;
      unsigned int ent = (idx < e0) ? entries[idx] : 0xFFFFFFFFu;
      bf16x8 a0, a1;
      if (ent != 0xFFFFFFFFu) {
        const __bf16* ar = inbf + ((size_t)(ent & 0x1FFFFu) << 6);
        a0 = *(const bf16x8*)(ar + quad * 8);
        a1 = *(const bf16x8*)(ar + 32 + quad * 8);
      } else {
#pragma unroll
        for (int j = 0; j < 8; ++j) { a0[j] = (__bf16)0.f; a1[j] = (__bf16)0.f; }
      }

      f32x4 acc[4];
#pragma unroll
      for (int nt = 0; nt < 4; ++nt) acc[nt] = (f32x4){0.f, 0.f, 0.f, 0.f};
#pragma unroll
      for (int nt = 0; nt < 4; ++nt) {
        acc[nt] = __builtin_amdgcn_mfma_f32_16x16x32_bf16(a0, bfrag[nt][0],
                                                          acc[nt], 0, 0, 0);
        acc[nt] = __builtin_amdgcn_mfma_f32_16x16x32_bf16(a1, bfrag[nt][1],
                                                          acc[nt], 0, 0, 0);
      }

      // C row m = quad*4 + r (entry m), col = nt*16 + (lane&15); invalid rows are 0.
#pragma unroll
      for (int r = 0; r < 4; ++r) {
        unsigned int entr = __shfl(ent, quad * 4 + r, 16);
        unsigned int ol = (entr == 0xFFFFFFFFu) ? 0u : (entr >> 17);
        float* dst = accs + ol * LDS_STRIDE + col;
#pragma unroll
        for (int nt = 0; nt < 4; ++nt)
          atomicAdd(dst + nt * 16, acc[nt][r]);
      }
    }
  }
  __syncthreads();

  const int rb = min(RPB, N_POINTS - b * RPB);
  for (int f = tid; f < RPB * 16; f += 256) {
    int row = f >> 4, c4 = f & 15;
    if (row < rb) {
      float4 a = *(const float4*)(accs + row * LDS_STRIDE + c4 * 4);
      float4 bv = ((const float4*)bias)[c4];
      float4 o;
      o.x = a.x + bv.x; o.y = a.y + bv.y; o.z = a.z + bv.z; o.w = a.w + bv.w;
      ((float4*)out)[(b * RPB + row) * 16 + c4] = o;
    }
  }
}

// ============================ fallback path (original) ============================

__global__ __launch_bounds__(256) void init_out_kernel(
    const float* __restrict__ bias, float* __restrict__ out) {
  int tid = blockIdx.x * blockDim.x + threadIdx.x;
  int c4 = tid & 15;
  float4 b = ((const float4*)bias)[c4];
  ((float4*)out)[tid] = b;
}

__global__ __launch_bounds__(256) void spconv_kernel(
    const float* __restrict__ input, const float* __restrict__ weight,
    const int* __restrict__ in_map, const int* __restrict__ out_map,
    float* __restrict__ out) {
  const int k = blockIdx.y;
  const int lane = threadIdx.x & 63;
  const int wave = threadIdx.x >> 6;
  const int col = lane & 15;
  const int quad = lane >> 4;

  const float* Wk = weight + k * (CCH * CCH);
  bf16x8 bfrag[4][2];
#pragma unroll
  for (int nt = 0; nt < 4; ++nt) {
    int co = nt * 16 + col;
#pragma unroll
    for (int s = 0; s < 2; ++s) {
      int ci0 = s * 32 + quad * 8;
      bf16x8 f;
#pragma unroll
      for (int j = 0; j < 8; ++j) f[j] = (__bf16)Wk[(ci0 + j) * CCH + co];
      bfrag[nt][s] = f;
    }
  }

  const int* im = in_map + k * PAIRS;
  const int* om = out_map + k * PAIRS;

  for (int tile = blockIdx.x * NWAVES + wave; tile < TILES_PER_K;
       tile += BX * NWAVES) {
    const int pbase = tile * 16;
    int rin = im[pbase + col];
    const float* arow = input + rin * CCH;
    bf16x8 afrag[2];
#pragma unroll
    for (int s = 0; s < 2; ++s) {
      const float4 x0 = *(const float4*)(arow + s * 32 + quad * 8);
      const float4 x1 = *(const float4*)(arow + s * 32 + quad * 8 + 4);
      bf16x8 f;
      f[0] = (__bf16)x0.x; f[1] = (__bf16)x0.y;
      f[2] = (__bf16)x0.z; f[3] = (__bf16)x0.w;
      f[4] = (__bf16)x1.x; f[5] = (__bf16)x1.y;
      f[6] = (__bf16)x1.z; f[7] = (__bf16)x1.w;
      afrag[s] = f;
    }

    f32x4 acc[4];
#pragma unroll
    for (int nt = 0; nt < 4; ++nt) acc[nt] = (f32x4){0.f, 0.f, 0.f, 0.f};
#pragma unroll
    for (int nt = 0; nt < 4; ++nt) {
      acc[nt] = __builtin_amdgcn_mfma_f32_16x16x32_bf16(afrag[0], bfrag[nt][0],
                                                        acc[nt], 0, 0, 0);
      acc[nt] = __builtin_amdgcn_mfma_f32_16x16x32_bf16(afrag[1], bfrag[nt][1],
                                                        acc[nt], 0, 0, 0);
    }

    int orow[4];
#pragma unroll
    for (int r = 0; r < 4; ++r) orow[r] = om[pbase + quad * 4 + r];
#pragma unroll
    for (int r = 0; r < 4; ++r) {
      float* op = out + orow[r] * CCH + col;
#pragma unroll
      for (int nt = 0; nt < 4; ++nt) atomicAdd(op + nt * 16, acc[nt][r]);
    }
  }
}

// ============================ launch ============================

extern "C" void kernel_launch(void* const* d_in, const int* in_sizes, int n_in,
                              void* d_out, int out_size, void* d_ws,
                              size_t ws_size, hipStream_t stream) {
  const float* input = (const float*)d_in[0];
  const float* weight = (const float*)d_in[1];
  const float* bias = (const float*)d_in[2];
  const int* in_map = (const int*)d_in[3];
  const int* out_map = (const int*)d_in[4];
  float* out = (float*)d_out;

  if (d_ws != nullptr && ws_size >= (size_t)WS_NEED) {
    unsigned char* ws = (unsigned char*)d_ws;
    prep_kernel<<<(N_POINTS * CCH / 4) / 256, 256, 0, stream>>>(input, weight, ws);
    hist_kernel<<<dim3((PAIRS + 255) / 256, K_VOL), 256, 0, stream>>>(out_map, ws);
    scan_kernel<<<1, SCAN_T, 0, stream>>>(ws);
    scatter_kernel<<<dim3((PAIRS + 255) / 256, K_VOL), 256, 0, stream>>>(in_map,
                                                                         out_map, ws);
    spconv_main_kernel<<<NBUCKETS, 256, 0, stream>>>(bias, ws, out);
  } else {
    init_out_kernel<<<(N_POINTS * 16) / 256, 256, 0, stream>>>(bias, out);
    dim3 grid(BX, K_VOL);
    spconv_kernel<<<grid, 256, 0, stream>>>(input, weight, in_map, out_map, out);
  }
}

// Round 4
// 576.898 us; speedup vs baseline: 1.8185x; 1.8185x over previous
//
#include <hip/hip_runtime.h>
#include <hip/hip_bf16.h>

#define N_POINTS 100000
#define K_VOL 27
#define PAIRS 60000
#define CCH 64                       // C_IN == C_OUT == 64
#define E_TOT (K_VOL * PAIRS)        // 1,620,000 entries
#define TILES_PER_K (PAIRS / 16)     // fallback path
#define BX 64                        // fallback path
#define NWAVES 4                     // fallback path

#define RPB 64                                     // rows per output bucket
#define NBUCKETS ((N_POINTS + RPB - 1) / RPB)      // 1563
#define NBINS (NBUCKETS * K_VOL)                   // 42201
#define NSH 8                                      // counter shards per bin
#define NBINS8 (NBINS * NSH)                       // 337608
#define SCANB ((NBINS8 + 1023) / 1024)             // 330
#define SENT 0xFFFFFFFFu

// workspace layout (bytes); cnt8 (NBINS8 u32) overlays the entries region
#define WS_ENTRIES 0
#define WS_OFF8 (E_TOT * 4)                        // 6,480,000
#define WS_PART (WS_OFF8 + NBINS8 * 4)             // 7,830,432
#define WS_INBF ((WS_PART + SCANB * 4 + 15) & ~15) // 7,831,760
#define WS_WT (WS_INBF + N_POINTS * CCH * 2)       // 20,631,760
#define WS_NEED (WS_WT + K_VOL * CCH * CCH * 2)    // 20,852,944 (~19.9 MiB)

typedef __bf16 bf16x8 __attribute__((ext_vector_type(8)));
typedef __bf16 bf16x4 __attribute__((ext_vector_type(4)));
typedef float f32x4 __attribute__((ext_vector_type(4)));

// ============================ new path ============================

// input f32 -> bf16 rows; weight f32 [k][ci][co] -> bf16 transposed wt[k][co][ci];
// zero the sharded bin counters (overlaid at WS_ENTRIES).
__global__ __launch_bounds__(256) void prep_kernel(
    const float* __restrict__ input, const float* __restrict__ weight,
    unsigned char* __restrict__ ws) {
  int t = blockIdx.x * 256 + threadIdx.x;  // exactly N*CCH/4 = 1,600,000 threads
  {
    float4 v = ((const float4*)input)[t];
    bf16x4 o;
    o[0] = (__bf16)v.x; o[1] = (__bf16)v.y; o[2] = (__bf16)v.z; o[3] = (__bf16)v.w;
    *(bf16x4*)(ws + WS_INBF + (size_t)t * 8) = o;
  }
  if (t < K_VOL * CCH * CCH) {             // 110592
    int k = t >> 12;
    int r = t & 4095;
    int ci = r >> 6, co = r & 63;
    *(__bf16*)(ws + WS_WT + (size_t)(((k * 64 + co) << 6) + ci) * 2) =
        (__bf16)weight[t];
  }
  if (t < NBINS8) {
    ((unsigned int*)(ws + WS_ENTRIES))[t] = 0u;   // cnt8 overlay
  }
}

// sharded histogram: ~4.8-way contention per counter instead of 77-way
__global__ __launch_bounds__(256) void hist_kernel(
    const int* __restrict__ out_map, unsigned char* __restrict__ ws) {
  int p = blockIdx.x * 256 + threadIdx.x;
  int k = blockIdx.y;
  if (p < PAIRS) {
    int om = out_map[k * PAIRS + p];
    int bin = (om >> 6) * K_VOL + k;
    atomicAdd((unsigned int*)(ws + WS_ENTRIES) + bin * NSH + (p & (NSH - 1)), 1u);
  }
}

// two-kernel parallel scan over cnt8 -> off8 (exclusive)
__global__ __launch_bounds__(1024) void scanA_kernel(unsigned char* __restrict__ ws) {
  __shared__ unsigned int red[1024];
  const unsigned int* cnt8 = (const unsigned int*)(ws + WS_ENTRIES);
  unsigned int* part = (unsigned int*)(ws + WS_PART);
  int t = threadIdx.x;
  int idx = blockIdx.x * 1024 + t;
  unsigned int v = (idx < NBINS8) ? cnt8[idx] : 0u;
  red[t] = v;
  __syncthreads();
  for (int d = 512; d > 0; d >>= 1) {
    if (t < d) red[t] += red[t + d];
    __syncthreads();
  }
  if (t == 0) part[blockIdx.x] = red[0];
}

__global__ __launch_bounds__(1024) void scanC_kernel(unsigned char* __restrict__ ws) {
  __shared__ unsigned int sc[1024];
  const unsigned int* cnt8 = (const unsigned int*)(ws + WS_ENTRIES);
  const unsigned int* part = (const unsigned int*)(ws + WS_PART);
  unsigned int* off8 = (unsigned int*)(ws + WS_OFF8);
  int t = threadIdx.x;
  int bx = blockIdx.x;
  unsigned int base = 0;
  for (int i = 0; i < bx; ++i) base += part[i];
  int idx = bx * 1024 + t;
  unsigned int v = (idx < NBINS8) ? cnt8[idx] : 0u;
  sc[t] = v;
  __syncthreads();
  for (int d = 1; d < 1024; d <<= 1) {
    unsigned int x = (t >= d) ? sc[t - d] : 0u;
    __syncthreads();
    sc[t] += x;
    __syncthreads();
  }
  if (idx < NBINS8) off8[idx] = base + sc[t] - v;   // exclusive
}

// counting-sort entries into (bucket,k,shard) order; off8 is destructively
// bumped to END offsets (main derives starts from the previous shard's end).
// entry = in_row (17b) | out_local (6b) << 17
__global__ __launch_bounds__(256) void scatter_kernel(
    const int* __restrict__ in_map, const int* __restrict__ out_map,
    unsigned char* __restrict__ ws) {
  int p = blockIdx.x * 256 + threadIdx.x;
  int k = blockIdx.y;
  if (p >= PAIRS) return;
  int om = out_map[k * PAIRS + p];
  int im = in_map[k * PAIRS + p];
  int bin = (om >> 6) * K_VOL + k;
  unsigned int pos =
      atomicAdd((unsigned int*)(ws + WS_OFF8) + bin * NSH + (p & (NSH - 1)), 1u);
  ((unsigned int*)(ws + WS_ENTRIES))[pos] =
      (unsigned int)im | ((unsigned int)(om & (RPB - 1)) << 17);
}

// One block per 64-row bucket; wave w owns output rows [16w,16w+16).
// Per 32-entry tile: C1 = gather(A) x W  (verified MFMA layout), round to bf16
// into per-wave LDS stage; build P^T (16x32 0/1) in per-wave LDS; then
// acc2 += P^T x C1 via a second MFMA -- the scatter IS a matmul.
// Zero atomics, zero barriers, zero shuffles in the loop.
__global__ __launch_bounds__(256) void spconv_main_kernel(
    const float* __restrict__ bias, const unsigned char* __restrict__ ws,
    float* __restrict__ out) {
  // per wave: stage 64 rows x 64 B (XOR-swizzled 16B slots) + pmat 16 x 64 B
  __shared__ __align__(16) unsigned char lds[4 * 5120];   // 20,480 B
  const unsigned int* off8 = (const unsigned int*)(ws + WS_OFF8);
  const unsigned int* entries = (const unsigned int*)(ws + WS_ENTRIES);
  const __bf16* inbf = (const __bf16*)(ws + WS_INBF);
  const __bf16* wt = (const __bf16*)(ws + WS_WT);

  const int b = blockIdx.x;
  const int tid = threadIdx.x;
  const int wave = tid >> 6, lane = tid & 63;
  const int c = lane & 15, q = lane >> 4;
  unsigned char* stage = lds + wave * 5120;
  unsigned char* pmat = stage + 4096;

  f32x4 acc2[4];
#pragma unroll
  for (int nt = 0; nt < 4; ++nt) acc2[nt] = (f32x4){0.f, 0.f, 0.f, 0.f};

  for (int kb = 0; kb < K_VOL; ++kb) {
    const int bin = b * K_VOL + kb;
    const int i8 = bin * NSH;
    const unsigned int s0 = (i8 == 0) ? 0u : off8[i8 - 1];
    const unsigned int e0 = off8[i8 + NSH - 1];
    if (s0 == e0) continue;

    bf16x8 bfrag[4][2];
#pragma unroll
    for (int nt = 0; nt < 4; ++nt) {
      const __bf16* wrow = wt + ((kb * 64 + nt * 16 + c) << 6);
#pragma unroll
      for (int s = 0; s < 2; ++s)
        bfrag[nt][s] = *(const bf16x8*)(wrow + s * 32 + q * 8);
    }

    for (unsigned int tb = s0; tb < e0; tb += 32) {
      const unsigned int i0 = tb + c, i1 = tb + 16 + c;
      const unsigned int ent0 = (i0 < e0) ? entries[i0] : SENT;
      const unsigned int ent1 = (i1 < e0) ? entries[i1] : SENT;

      // zero pmat (1024 B = 64 lanes x 16 B), then mark this wave's rows
      *(f32x4*)(pmat + lane * 16) = (f32x4){0.f, 0.f, 0.f, 0.f};

      bf16x8 a00, a01, a10, a11;
      if (ent0 != SENT) {
        const __bf16* ar = inbf + ((size_t)(ent0 & 0x1FFFFu) << 6);
        a00 = *(const bf16x8*)(ar + q * 8);
        a01 = *(const bf16x8*)(ar + 32 + q * 8);
      } else {
#pragma unroll
        for (int j = 0; j < 8; ++j) { a00[j] = (__bf16)0.f; a01[j] = (__bf16)0.f; }
      }
      if (ent1 != SENT) {
        const __bf16* ar = inbf + ((size_t)(ent1 & 0x1FFFFu) << 6);
        a10 = *(const bf16x8*)(ar + q * 8);
        a11 = *(const bf16x8*)(ar + 32 + q * 8);
      } else {
#pragma unroll
        for (int j = 0; j < 8; ++j) { a10[j] = (__bf16)0.f; a11[j] = (__bf16)0.f; }
      }

      // P^T[ol][m] = 1 iff entry m -> this wave's local row ol. Distinct m =>
      // distinct addresses: plain ds_write_b16, no atomics.
      if (q == 0 && ent0 != SENT) {
        int ol = (int)(ent0 >> 17) - wave * 16;
        if ((unsigned)ol < 16u) {
          int m = c;
          *(__bf16*)(pmat + ol * 64 + (((m >> 3) ^ (ol & 3)) << 4) + (m & 7) * 2) =
              (__bf16)1.0f;
        }
      }
      if (q == 1 && ent1 != SENT) {
        int ol = (int)(ent1 >> 17) - wave * 16;
        if ((unsigned)ol < 16u) {
          int m = 16 + c;
          *(__bf16*)(pmat + ol * 64 + (((m >> 3) ^ (ol & 3)) << 4) + (m & 7) * 2) =
              (__bf16)1.0f;
        }
      }

      // C1 = A x W for both 16-entry half-tiles (layouts verified in v0 kernel)
      f32x4 c1a[4], c1b[4];
#pragma unroll
      for (int nt = 0; nt < 4; ++nt) {
        c1a[nt] = (f32x4){0.f, 0.f, 0.f, 0.f};
        c1b[nt] = (f32x4){0.f, 0.f, 0.f, 0.f};
      }
#pragma unroll
      for (int nt = 0; nt < 4; ++nt) {
        c1a[nt] = __builtin_amdgcn_mfma_f32_16x16x32_bf16(a00, bfrag[nt][0],
                                                          c1a[nt], 0, 0, 0);
        c1a[nt] = __builtin_amdgcn_mfma_f32_16x16x32_bf16(a01, bfrag[nt][1],
                                                          c1a[nt], 0, 0, 0);
        c1b[nt] = __builtin_amdgcn_mfma_f32_16x16x32_bf16(a10, bfrag[nt][0],
                                                          c1b[nt], 0, 0, 0);
        c1b[nt] = __builtin_amdgcn_mfma_f32_16x16x32_bf16(a11, bfrag[nt][1],
                                                          c1b[nt], 0, 0, 0);
      }

      // stage C1 as bf16: layout [n:64][m:32] with 16B-slot XOR swizzle
      // (slot ^= n&3) -> ~4-way worst-case bank aliasing instead of 8-way
#pragma unroll
      for (int nt = 0; nt < 4; ++nt) {
        const int n = nt * 16 + c;
        const int swz = n & 3;
        const int in0 = (q & 1) * 8;
        bf16x4 h0, h1;
#pragma unroll
        for (int r = 0; r < 4; ++r) {
          h0[r] = (__bf16)c1a[nt][r];
          h1[r] = (__bf16)c1b[nt][r];
        }
        *(bf16x4*)(stage + n * 64 + (((q >> 1) ^ swz) << 4) + in0) = h0;        // m0=4q
        *(bf16x4*)(stage + n * 64 + (((2 + (q >> 1)) ^ swz) << 4) + in0) = h1;  // m0=16+4q
      }

      // second MFMA: acc2 += P^T (16x32) x C1 (32x64)
      const bf16x8 pa = *(const bf16x8*)(pmat + c * 64 + ((q ^ (c & 3)) << 4));
#pragma unroll
      for (int nt = 0; nt < 4; ++nt) {
        const int n = nt * 16 + c;
        const bf16x8 bb = *(const bf16x8*)(stage + n * 64 + ((q ^ (n & 3)) << 4));
        acc2[nt] = __builtin_amdgcn_mfma_f32_16x16x32_bf16(pa, bb, acc2[nt], 0, 0, 0);
      }
    }
  }

  // each wave owns disjoint rows: plain coalesced stores, +bias
  const int row0 = b * RPB + wave * 16 + q * 4;
  float bv[4];
#pragma unroll
  for (int nt = 0; nt < 4; ++nt) bv[nt] = bias[nt * 16 + c];
#pragma unroll
  for (int r = 0; r < 4; ++r) {
    const int row = row0 + r;
    if (row < N_POINTS) {
#pragma unroll
      for (int nt = 0; nt < 4; ++nt)
        out[row * CCH + nt * 16 + c] = acc2[nt][r] + bv[nt];
    }
  }
}

// ============================ fallback path (original) ============================

__global__ __launch_bounds__(256) void init_out_kernel(
    const float* __restrict__ bias, float* __restrict__ out) {
  int tid = blockIdx.x * blockDim.x + threadIdx.x;
  int c4 = tid & 15;
  float4 b = ((const float4*)bias)[c4];
  ((float4*)out)[tid] = b;
}

__global__ __launch_bounds__(256) void spconv_kernel(
    const float* __restrict__ input, const float* __restrict__ weight,
    const int* __restrict__ in_map, const int* __restrict__ out_map,
    float* __restrict__ out) {
  const int k = blockIdx.y;
  const int lane = threadIdx.x & 63;
  const int wave = threadIdx.x >> 6;
  const int col = lane & 15;
  const int quad = lane >> 4;

  const float* Wk = weight + k * (CCH * CCH);
  bf16x8 bfrag[4][2];
#pragma unroll
  for (int nt = 0; nt < 4; ++nt) {
    int co = nt * 16 + col;
#pragma unroll
    for (int s = 0; s < 2; ++s) {
      int ci0 = s * 32 + quad * 8;
      bf16x8 f;
#pragma unroll
      for (int j = 0; j < 8; ++j) f[j] = (__bf16)Wk[(ci0 + j) * CCH + co];
      bfrag[nt][s] = f;
    }
  }

  const int* im = in_map + k * PAIRS;
  const int* om = out_map + k * PAIRS;

  for (int tile = blockIdx.x * NWAVES + wave; tile < TILES_PER_K;
       tile += BX * NWAVES) {
    const int pbase = tile * 16;
    int rin = im[pbase + col];
    const float* arow = input + rin * CCH;
    bf16x8 afrag[2];
#pragma unroll
    for (int s = 0; s < 2; ++s) {
      const float4 x0 = *(const float4*)(arow + s * 32 + quad * 8);
      const float4 x1 = *(const float4*)(arow + s * 32 + quad * 8 + 4);
      bf16x8 f;
      f[0] = (__bf16)x0.x; f[1] = (__bf16)x0.y;
      f[2] = (__bf16)x0.z; f[3] = (__bf16)x0.w;
      f[4] = (__bf16)x1.x; f[5] = (__bf16)x1.y;
      f[6] = (__bf16)x1.z; f[7] = (__bf16)x1.w;
      afrag[s] = f;
    }

    f32x4 acc[4];
#pragma unroll
    for (int nt = 0; nt < 4; ++nt) acc[nt] = (f32x4){0.f, 0.f, 0.f, 0.f};
#pragma unroll
    for (int nt = 0; nt < 4; ++nt) {
      acc[nt] = __builtin_amdgcn_mfma_f32_16x16x32_bf16(afrag[0], bfrag[nt][0],
                                                        acc[nt], 0, 0, 0);
      acc[nt] = __builtin_amdgcn_mfma_f32_16x16x32_bf16(afrag[1], bfrag[nt][1],
                                                        acc[nt], 0, 0, 0);
    }

    int orow[4];
#pragma unroll
    for (int r = 0; r < 4; ++r) orow[r] = om[pbase + quad * 4 + r];
#pragma unroll
    for (int r = 0; r < 4; ++r) {
      float* op = out + orow[r] * CCH + col;
#pragma unroll
      for (int nt = 0; nt < 4; ++nt) atomicAdd(op + nt * 16, acc[nt][r]);
    }
  }
}

// ============================ launch ============================

extern "C" void kernel_launch(void* const* d_in, const int* in_sizes, int n_in,
                              void* d_out, int out_size, void* d_ws,
                              size_t ws_size, hipStream_t stream) {
  const float* input = (const float*)d_in[0];
  const float* weight = (const float*)d_in[1];
  const float* bias = (const float*)d_in[2];
  const int* in_map = (const int*)d_in[3];
  const int* out_map = (const int*)d_in[4];
  float* out = (float*)d_out;

  if (d_ws != nullptr && ws_size >= (size_t)WS_NEED) {
    unsigned char* ws = (unsigned char*)d_ws;
    prep_kernel<<<(N_POINTS * CCH / 4) / 256, 256, 0, stream>>>(input, weight, ws);
    hist_kernel<<<dim3((PAIRS + 255) / 256, K_VOL), 256, 0, stream>>>(out_map, ws);
    scanA_kernel<<<SCANB, 1024, 0, stream>>>(ws);
    scanC_kernel<<<SCANB, 1024, 0, stream>>>(ws);
    scatter_kernel<<<dim3((PAIRS + 255) / 256, K_VOL), 256, 0, stream>>>(in_map,
                                                                         out_map, ws);
    spconv_main_kernel<<<NBUCKETS, 256, 0, stream>>>(bias, ws, out);
  } else {
    init_out_kernel<<<(N_POINTS * 16) / 256, 256, 0, stream>>>(bias, out);
    dim3 grid(BX, K_VOL);
    spconv_kernel<<<grid, 256, 0, stream>>>(input, weight, in_map, out_map, out);
  }
}

// Round 5
// 375.933 us; speedup vs baseline: 2.7906x; 1.5346x over previous
//
#include <hip/hip_runtime.h>
#include <hip/hip_bf16.h>

#define N_POINTS 100000
#define K_VOL 27
#define PAIRS 60000
#define CCH 64                       // C_IN == C_OUT == 64
#define TILES_PER_K (PAIRS / 16)     // fallback path
#define BX 64                        // fallback path
#define NWAVES 4                     // fallback path

#define RPB 64                                     // rows per output bucket
#define NBUCKETS ((N_POINTS + RPB - 1) / RPB)      // 1563
#define NBINS (NBUCKETS * K_VOL)                   // 42201
#define CAP 96                                     // bin capacity (lambda=38.4, 96=+9sigma)
#define SENT 0xFFFFFFFFu

// workspace layout (bytes)
#define WS_ENT 0
#define WS_CNT (NBINS * CAP * 4)                   // 16,205,184
#define WS_INBF ((WS_CNT + NBINS * 4 + 15) & ~15)  // 16,374,000
#define WS_WT (WS_INBF + N_POINTS * CCH * 2)       // 29,174,000
#define WS_NEED (WS_WT + K_VOL * CCH * CCH * 2)    // 29,395,184 (~28.0 MiB)

typedef __bf16 bf16x8 __attribute__((ext_vector_type(8)));
typedef __bf16 bf16x4 __attribute__((ext_vector_type(4)));
typedef float f32x4 __attribute__((ext_vector_type(4)));

// ============================ new path ============================

// input f32 -> bf16 rows; weight f32 [k][ci][co] -> bf16 transposed wt[k][co][ci];
// zero the bin counters.
__global__ __launch_bounds__(256) void prep_kernel(
    const float* __restrict__ input, const float* __restrict__ weight,
    unsigned char* __restrict__ ws) {
  int t = blockIdx.x * 256 + threadIdx.x;  // exactly N*CCH/4 = 1,600,000 threads
  {
    float4 v = ((const float4*)input)[t];
    bf16x4 o;
    o[0] = (__bf16)v.x; o[1] = (__bf16)v.y; o[2] = (__bf16)v.z; o[3] = (__bf16)v.w;
    *(bf16x4*)(ws + WS_INBF + (size_t)t * 8) = o;
  }
  if (t < K_VOL * CCH * CCH) {             // 110592
    int k = t >> 12;
    int r = t & 4095;
    int ci = r >> 6, co = r & 63;
    *(__bf16*)(ws + WS_WT + (size_t)(((k * 64 + co) << 6) + ci) * 2) =
        (__bf16)weight[t];
  }
  if (t < NBINS) {
    ((unsigned int*)(ws + WS_CNT))[t] = 0u;
  }
}

// single-pass binning: bump-allocate into fixed-capacity bins.
// entry = in_row (17b) | out_local (6b) << 17
__global__ __launch_bounds__(256) void fill_kernel(
    const int* __restrict__ in_map, const int* __restrict__ out_map,
    unsigned char* __restrict__ ws) {
  int p = blockIdx.x * 256 + threadIdx.x;
  int k = blockIdx.y;
  if (p >= PAIRS) return;
  int om = out_map[k * PAIRS + p];
  int im = in_map[k * PAIRS + p];
  int bin = (om >> 6) * K_VOL + k;
  unsigned int pos = atomicAdd((unsigned int*)(ws + WS_CNT) + bin, 1u);
  if (pos < CAP)
    ((unsigned int*)(ws + WS_ENT))[bin * CAP + pos] =
        (unsigned int)im | ((unsigned int)(om & (RPB - 1)) << 17);
}

// 4 waves/block = 2 buckets/block; wave w owns 32 rows of bucket 2*bx+(w>>1).
// Per 32-entry tile: C1 = gather(A) x W -> bf16 in per-wave LDS stage;
// P^T (32x32 0/1) in per-wave LDS; acc2 += P^T x C1 (8 MFMA) -- the
// scatter IS a matmul. Zero atomics, barriers, shuffles.
__global__ __launch_bounds__(256) void spconv_main_kernel(
    const float* __restrict__ bias, const unsigned char* __restrict__ ws,
    float* __restrict__ out) {
  // per wave: stage 64 n x 64 B (XOR-swizzled 16B slots) + pmat 32 x 64 B
  __shared__ __align__(16) unsigned char lds[4 * 6144];   // 24,576 B
  const unsigned int* cnt = (const unsigned int*)(ws + WS_CNT);
  const unsigned int* entries = (const unsigned int*)(ws + WS_ENT);
  const __bf16* inbf = (const __bf16*)(ws + WS_INBF);
  const __bf16* wt = (const __bf16*)(ws + WS_WT);

  const int tid = threadIdx.x;
  const int wave = tid >> 6, lane = tid & 63;
  const int c = lane & 15, q = lane >> 4;
  const int bucket = blockIdx.x * 2 + (wave >> 1);
  unsigned char* stage = lds + wave * 6144;
  unsigned char* pmat = stage + 4096;

  f32x4 acc2[2][4];
#pragma unroll
  for (int rb = 0; rb < 2; ++rb)
#pragma unroll
    for (int nt = 0; nt < 4; ++nt) acc2[rb][nt] = (f32x4){0.f, 0.f, 0.f, 0.f};

  if (bucket < NBUCKETS) {
    for (int kb = 0; kb < K_VOL; ++kb) {
      const int bin = bucket * K_VOL + kb;
      unsigned int e0 = cnt[bin];
      if (e0 == 0) continue;
      if (e0 > CAP) e0 = CAP;   // paranoia clamp (P ~ 1e-9)

      bf16x8 bfrag[4][2];
#pragma unroll
      for (int nt = 0; nt < 4; ++nt) {
        const __bf16* wrow = wt + ((kb * 64 + nt * 16 + c) << 6);
#pragma unroll
        for (int s = 0; s < 2; ++s)
          bfrag[nt][s] = *(const bf16x8*)(wrow + s * 32 + q * 8);
      }

      const unsigned int* base = entries + bin * CAP;

      for (unsigned int tb = 0; tb < e0; tb += 32) {
        const unsigned int i0 = tb + c, i1 = tb + 16 + c;
        const unsigned int ent0 = (i0 < e0) ? base[i0] : SENT;
        const unsigned int ent1 = (i1 < e0) ? base[i1] : SENT;

        // zero pmat (2048 B = 64 lanes x 32 B)
        *(f32x4*)(pmat + lane * 32) = (f32x4){0.f, 0.f, 0.f, 0.f};
        *(f32x4*)(pmat + lane * 32 + 16) = (f32x4){0.f, 0.f, 0.f, 0.f};

        bf16x8 a00, a01, a10, a11;
        if (ent0 != SENT) {
          const __bf16* ar = inbf + ((size_t)(ent0 & 0x1FFFFu) << 6);
          a00 = *(const bf16x8*)(ar + q * 8);
          a01 = *(const bf16x8*)(ar + 32 + q * 8);
        } else {
#pragma unroll
          for (int j = 0; j < 8; ++j) { a00[j] = (__bf16)0.f; a01[j] = (__bf16)0.f; }
        }
        if (ent1 != SENT) {
          const __bf16* ar = inbf + ((size_t)(ent1 & 0x1FFFFu) << 6);
          a10 = *(const bf16x8*)(ar + q * 8);
          a11 = *(const bf16x8*)(ar + 32 + q * 8);
        } else {
#pragma unroll
          for (int j = 0; j < 8; ++j) { a10[j] = (__bf16)0.f; a11[j] = (__bf16)0.f; }
        }

        // P^T[ol][m] = 1 iff entry m -> this wave's local row ol in [0,32).
        // Distinct m => distinct addresses: plain ds_write_b16, no atomics.
        if (q == 0 && ent0 != SENT) {
          int ol = (int)(ent0 >> 17) - (wave & 1) * 32;
          if ((unsigned)ol < 32u) {
            int m = c;
            *(__bf16*)(pmat + ol * 64 + (((m >> 3) ^ (ol & 3)) << 4) + (m & 7) * 2) =
                (__bf16)1.0f;
          }
        }
        if (q == 1 && ent1 != SENT) {
          int ol = (int)(ent1 >> 17) - (wave & 1) * 32;
          if ((unsigned)ol < 32u) {
            int m = 16 + c;
            *(__bf16*)(pmat + ol * 64 + (((m >> 3) ^ (ol & 3)) << 4) + (m & 7) * 2) =
                (__bf16)1.0f;
          }
        }

        // C1 = A x W for both 16-entry half-tiles (layouts verified)
        f32x4 c1a[4], c1b[4];
#pragma unroll
        for (int nt = 0; nt < 4; ++nt) {
          c1a[nt] = (f32x4){0.f, 0.f, 0.f, 0.f};
          c1b[nt] = (f32x4){0.f, 0.f, 0.f, 0.f};
        }
#pragma unroll
        for (int nt = 0; nt < 4; ++nt) {
          c1a[nt] = __builtin_amdgcn_mfma_f32_16x16x32_bf16(a00, bfrag[nt][0],
                                                            c1a[nt], 0, 0, 0);
          c1a[nt] = __builtin_amdgcn_mfma_f32_16x16x32_bf16(a01, bfrag[nt][1],
                                                            c1a[nt], 0, 0, 0);
          c1b[nt] = __builtin_amdgcn_mfma_f32_16x16x32_bf16(a10, bfrag[nt][0],
                                                            c1b[nt], 0, 0, 0);
          c1b[nt] = __builtin_amdgcn_mfma_f32_16x16x32_bf16(a11, bfrag[nt][1],
                                                            c1b[nt], 0, 0, 0);
        }

        // stage C1 as bf16: [n:64][m:32], 16B-slot XOR swizzle (slot ^= n&3)
#pragma unroll
        for (int nt = 0; nt < 4; ++nt) {
          const int n = nt * 16 + c;
          const int swz = n & 3;
          const int in0 = (q & 1) * 8;
          bf16x4 h0, h1;
#pragma unroll
          for (int r = 0; r < 4; ++r) {
            h0[r] = (__bf16)c1a[nt][r];
            h1[r] = (__bf16)c1b[nt][r];
          }
          *(bf16x4*)(stage + n * 64 + (((q >> 1) ^ swz) << 4) + in0) = h0;
          *(bf16x4*)(stage + n * 64 + (((2 + (q >> 1)) ^ swz) << 4) + in0) = h1;
        }

        // scatter: acc2[rb] += P^T rows [16rb,16rb+16) (16x32) x C1 (32x64)
        bf16x8 pa[2];
#pragma unroll
        for (int rb = 0; rb < 2; ++rb)
          pa[rb] = *(const bf16x8*)(pmat + (rb * 16 + c) * 64 + ((q ^ (c & 3)) << 4));
#pragma unroll
        for (int nt = 0; nt < 4; ++nt) {
          const int n = nt * 16 + c;
          const bf16x8 bb = *(const bf16x8*)(stage + n * 64 + ((q ^ (n & 3)) << 4));
          acc2[0][nt] = __builtin_amdgcn_mfma_f32_16x16x32_bf16(pa[0], bb,
                                                               acc2[0][nt], 0, 0, 0);
          acc2[1][nt] = __builtin_amdgcn_mfma_f32_16x16x32_bf16(pa[1], bb,
                                                               acc2[1][nt], 0, 0, 0);
        }
      }
    }
  }

  // each wave owns disjoint rows: plain coalesced stores, +bias
  const int row0 = bucket * RPB + (wave & 1) * 32 + q * 4;
  float bv[4];
#pragma unroll
  for (int nt = 0; nt < 4; ++nt) bv[nt] = bias[nt * 16 + c];
#pragma unroll
  for (int rb = 0; rb < 2; ++rb) {
#pragma unroll
    for (int r = 0; r < 4; ++r) {
      const int row = row0 + rb * 16 + r;
      if (row < N_POINTS) {
#pragma unroll
        for (int nt = 0; nt < 4; ++nt)
          out[row * CCH + nt * 16 + c] = acc2[rb][nt][r] + bv[nt];
      }
    }
  }
}

// ============================ fallback path (original) ============================

__global__ __launch_bounds__(256) void init_out_kernel(
    const float* __restrict__ bias, float* __restrict__ out) {
  int tid = blockIdx.x * blockDim.x + threadIdx.x;
  int c4 = tid & 15;
  float4 b = ((const float4*)bias)[c4];
  ((float4*)out)[tid] = b;
}

__global__ __launch_bounds__(256) void spconv_kernel(
    const float* __restrict__ input, const float* __restrict__ weight,
    const int* __restrict__ in_map, const int* __restrict__ out_map,
    float* __restrict__ out) {
  const int k = blockIdx.y;
  const int lane = threadIdx.x & 63;
  const int wave = threadIdx.x >> 6;
  const int col = lane & 15;
  const int quad = lane >> 4;

  const float* Wk = weight + k * (CCH * CCH);
  bf16x8 bfrag[4][2];
#pragma unroll
  for (int nt = 0; nt < 4; ++nt) {
    int co = nt * 16 + col;
#pragma unroll
    for (int s = 0; s < 2; ++s) {
      int ci0 = s * 32 + quad * 8;
      bf16x8 f;
#pragma unroll
      for (int j = 0; j < 8; ++j) f[j] = (__bf16)Wk[(ci0 + j) * CCH + co];
      bfrag[nt][s] = f;
    }
  }

  const int* im = in_map + k * PAIRS;
  const int* om = out_map + k * PAIRS;

  for (int tile = blockIdx.x * NWAVES + wave; tile < TILES_PER_K;
       tile += BX * NWAVES) {
    const int pbase = tile * 16;
    int rin = im[pbase + col];
    const float* arow = input + rin * CCH;
    bf16x8 afrag[2];
#pragma unroll
    for (int s = 0; s < 2; ++s) {
      const float4 x0 = *(const float4*)(arow + s * 32 + quad * 8);
      const float4 x1 = *(const float4*)(arow + s * 32 + quad * 8 + 4);
      bf16x8 f;
      f[0] = (__bf16)x0.x; f[1] = (__bf16)x0.y;
      f[2] = (__bf16)x0.z; f[3] = (__bf16)x0.w;
      f[4] = (__bf16)x1.x; f[5] = (__bf16)x1.y;
      f[6] = (__bf16)x1.z; f[7] = (__bf16)x1.w;
      afrag[s] = f;
    }

    f32x4 acc[4];
#pragma unroll
    for (int nt = 0; nt < 4; ++nt) acc[nt] = (f32x4){0.f, 0.f, 0.f, 0.f};
#pragma unroll
    for (int nt = 0; nt < 4; ++nt) {
      acc[nt] = __builtin_amdgcn_mfma_f32_16x16x32_bf16(afrag[0], bfrag[nt][0],
                                                        acc[nt], 0, 0, 0);
      acc[nt] = __builtin_amdgcn_mfma_f32_16x16x32_bf16(afrag[1], bfrag[nt][1],
                                                        acc[nt], 0, 0, 0);
    }

    int orow[4];
#pragma unroll
    for (int r = 0; r < 4; ++r) orow[r] = om[pbase + quad * 4 + r];
#pragma unroll
    for (int r = 0; r < 4; ++r) {
      float* op = out + orow[r] * CCH + col;
#pragma unroll
      for (int nt = 0; nt < 4; ++nt) atomicAdd(op + nt * 16, acc[nt][r]);
    }
  }
}

// ============================ launch ============================

extern "C" void kernel_launch(void* const* d_in, const int* in_sizes, int n_in,
                              void* d_out, int out_size, void* d_ws,
                              size_t ws_size, hipStream_t stream) {
  const float* input = (const float*)d_in[0];
  const float* weight = (const float*)d_in[1];
  const float* bias = (const float*)d_in[2];
  const int* in_map = (const int*)d_in[3];
  const int* out_map = (const int*)d_in[4];
  float* out = (float*)d_out;

  if (d_ws != nullptr && ws_size >= (size_t)WS_NEED) {
    unsigned char* ws = (unsigned char*)d_ws;
    prep_kernel<<<(N_POINTS * CCH / 4) / 256, 256, 0, stream>>>(input, weight, ws);
    fill_kernel<<<dim3((PAIRS + 255) / 256, K_VOL), 256, 0, stream>>>(in_map,
                                                                      out_map, ws);
    spconv_main_kernel<<<(NBUCKETS + 1) / 2, 256, 0, stream>>>(bias, ws, out);
  } else {
    init_out_kernel<<<(N_POINTS * 16) / 256, 256, 0, stream>>>(bias, out);
    dim3 grid(BX, K_VOL);
    spconv_kernel<<<grid, 256, 0, stream>>>(input, weight, in_map, out_map, out);
  }
}

// Round 7
// 317.462 us; speedup vs baseline: 3.3046x; 1.1842x over previous
//
#include <hip/hip_runtime.h>
#include <hip/hip_bf16.h>

#define N_POINTS 100000
#define K_VOL 27
#define PAIRS 60000
#define CCH 64                       // C_IN == C_OUT == 64
#define TILES_PER_K (PAIRS / 16)     // fallback path
#define BX 64                        // fallback path
#define NWAVES 4                     // fallback path

#define RPB 64                                     // rows per output bucket
#define NBUCKETS ((N_POINTS + RPB - 1) / RPB)      // 1563
#define NBINS (NBUCKETS * K_VOL)                   // 42201
#define CAP 96                                     // bin capacity (lambda=38.4)
#define SENT 0xFFFFFFFFu

#define PREP_BLKS 6250                             // 1.6M threads for input cvt
#define FILLB_PER_K 59                             // ceil(60000/1024)
#define FILL_BLKS (K_VOL * FILLB_PER_K)            // 1593

// workspace layout (bytes)
#define WS_ENT 0
#define WS_CNT (NBINS * CAP * 4)                   // 16,205,184
#define WS_INBF ((WS_CNT + NBINS * 4 + 15) & ~15)  // 16,374,000
#define WS_WT (WS_INBF + N_POINTS * CCH * 2)       // 29,174,000
#define WS_NEED (WS_WT + K_VOL * CCH * CCH * 2)    // 29,395,184 (~28.0 MiB)

typedef __bf16 bf16x8 __attribute__((ext_vector_type(8)));
typedef __bf16 bf16x4 __attribute__((ext_vector_type(4)));
typedef float f32x4 __attribute__((ext_vector_type(4)));

// ============================ new path ============================

// Fused: blocks [0,PREP_BLKS) convert input f32->bf16 + transpose weights to
// bf16 wt[k][co][ci]; blocks [PREP_BLKS,..) bin the pairs (cnt pre-zeroed by
// hipMemsetAsync). The two roles touch disjoint data -> safe to run fused.
// entry = in_row (17b) | out_local (6b) << 17
__global__ __launch_bounds__(256) void prep_fill_kernel(
    const float* __restrict__ input, const float* __restrict__ weight,
    const int* __restrict__ in_map, const int* __restrict__ out_map,
    unsigned char* __restrict__ ws) {
  const int bid = blockIdx.x;
  if (bid < PREP_BLKS) {
    int t = bid * 256 + threadIdx.x;  // exactly N*CCH/4 = 1,600,000 threads
    float4 v = ((const float4*)input)[t];
    bf16x4 o;
    o[0] = (__bf16)v.x; o[1] = (__bf16)v.y; o[2] = (__bf16)v.z; o[3] = (__bf16)v.w;
    *(bf16x4*)(ws + WS_INBF + (size_t)t * 8) = o;
    if (t < K_VOL * CCH * CCH) {             // 110592
      int k = t >> 12;
      int r = t & 4095;
      int ci = r >> 6, co = r & 63;
      *(__bf16*)(ws + WS_WT + (size_t)(((k * 64 + co) << 6) + ci) * 2) =
          (__bf16)weight[t];
    }
  } else {
    int fb = bid - PREP_BLKS;
    int k = fb / FILLB_PER_K;
    int pb = fb - k * FILLB_PER_K;
    int p = pb * 1024 + (int)threadIdx.x * 4;
    if (p < PAIRS) {
      int4 om4 = *(const int4*)(out_map + k * PAIRS + p);
      int4 im4 = *(const int4*)(in_map + k * PAIRS + p);
      unsigned int* cntp = (unsigned int*)(ws + WS_CNT);
      unsigned int* entp = (unsigned int*)(ws + WS_ENT);
      int oms[4] = {om4.x, om4.y, om4.z, om4.w};
      int ims[4] = {im4.x, im4.y, im4.z, im4.w};
#pragma unroll
      for (int j = 0; j < 4; ++j) {
        int bin = (oms[j] >> 6) * K_VOL + k;
        unsigned int pos = atomicAdd(cntp + bin, 1u);
        if (pos < CAP)
          entp[bin * CAP + pos] =
              (unsigned int)ims[j] | ((unsigned int)(oms[j] & 63) << 17);
      }
    }
  }
}

// One block per 64-row bucket. Wave w owns ALL 64 rows but only k-bins
// {w, w+4, ...} -> every entry-tile is processed by exactly ONE wave (1x
// redundancy). Per 32-entry tile: C1 = gather(A) x W (8 MFMA) -> bf16 LDS
// stage; P^T (64x32 0/1, persistent LDS, mark/unmark) ; acc += P^T x C1
// (16 MFMA). Final cross-wave LDS tree-reduce, single coalesced store+bias.
// Zero atomics / barriers / shuffles in the hot loop.
// NOTE: no min-waves bound -- acc(64 AGPR)+bfrag(32)+temps needs ~160 regs;
// forcing 5 waves/EU (<=102) would spill the accumulators to scratch.
__global__ __launch_bounds__(256) void spconv_main_kernel(
    const float* __restrict__ bias, const unsigned char* __restrict__ ws,
    float* __restrict__ out) {
  // per wave: stage 4096 B (64 n x 64 B, XOR-swizzled 16B slots)
  //           + pmat 4096 B (64 ol x 64 B). Reduce phase reuses all 32 KB.
  __shared__ __align__(16) unsigned char lds[4 * 8192];   // 32,768 B
  const unsigned int* cnt = (const unsigned int*)(ws + WS_CNT);
  const unsigned int* entries = (const unsigned int*)(ws + WS_ENT);
  const __bf16* inbf = (const __bf16*)(ws + WS_INBF);
  const __bf16* wt = (const __bf16*)(ws + WS_WT);

  const int b = blockIdx.x;
  const int tid = threadIdx.x;
  const int wave = tid >> 6, lane = tid & 63;
  const int c = lane & 15, q = lane >> 4;
  unsigned char* stage = lds + wave * 8192;
  unsigned char* pmat = stage + 4096;

  // zero this wave's pmat ONCE: b32 stride-1 across lanes = conflict-free
#pragma unroll
  for (int i = 0; i < 16; ++i)
    *(float*)(pmat + i * 256 + lane * 4) = 0.f;

  f32x4 acc[4][4];
#pragma unroll
  for (int rb = 0; rb < 4; ++rb)
#pragma unroll
    for (int nt = 0; nt < 4; ++nt) acc[rb][nt] = (f32x4){0.f, 0.f, 0.f, 0.f};

  for (int kb = wave; kb < K_VOL; kb += 4) {
    const int bin = b * K_VOL + kb;
    unsigned int e0 = cnt[bin];
    if (e0 == 0) continue;
    if (e0 > CAP) e0 = CAP;

    bf16x8 bfrag[4][2];
#pragma unroll
    for (int nt = 0; nt < 4; ++nt) {
      const __bf16* wrow = wt + ((kb * 64 + nt * 16 + c) << 6);
#pragma unroll
      for (int s = 0; s < 2; ++s)
        bfrag[nt][s] = *(const bf16x8*)(wrow + s * 32 + q * 8);
    }

    const unsigned int* base = entries + bin * CAP;

    for (unsigned int tb = 0; tb < e0; tb += 32) {
      const unsigned int i0 = tb + c, i1 = tb + 16 + c;
      const unsigned int ent0 = (i0 < e0) ? base[i0] : SENT;
      const unsigned int ent1 = (i1 < e0) ? base[i1] : SENT;

      // invalid entries: gather row 0 (value irrelevant -- their P^T column
      // is all-zero), avoiding a branchy zero-fill
      const unsigned int r0 = (ent0 == SENT) ? 0u : (ent0 & 0x1FFFFu);
      const unsigned int r1 = (ent1 == SENT) ? 0u : (ent1 & 0x1FFFFu);
      const __bf16* ar0 = inbf + ((size_t)r0 << 6);
      const __bf16* ar1 = inbf + ((size_t)r1 << 6);
      bf16x8 a00 = *(const bf16x8*)(ar0 + q * 8);
      bf16x8 a01 = *(const bf16x8*)(ar0 + 32 + q * 8);
      bf16x8 a10 = *(const bf16x8*)(ar1 + q * 8);
      bf16x8 a11 = *(const bf16x8*)(ar1 + 32 + q * 8);

      // mark P^T[ol][m]=1 (distinct m => distinct addresses, plain b16 write)
      int mol0 = -1, mol1 = -1;
      if (q == 0 && ent0 != SENT) mol0 = (int)(ent0 >> 17);
      if (q == 1 && ent1 != SENT) mol1 = (int)(ent1 >> 17);
      if (mol0 >= 0) {
        int m = c;
        *(__bf16*)(pmat + mol0 * 64 + (((m >> 3) ^ (mol0 & 3)) << 4) + (m & 7) * 2) =
            (__bf16)1.0f;
      }
      if (mol1 >= 0) {
        int m = 16 + c;
        *(__bf16*)(pmat + mol1 * 64 + (((m >> 3) ^ (mol1 & 3)) << 4) + (m & 7) * 2) =
            (__bf16)1.0f;
      }

      // C1 = A x W for both 16-entry half-tiles
      f32x4 c1a[4], c1b[4];
#pragma unroll
      for (int nt = 0; nt < 4; ++nt) {
        c1a[nt] = (f32x4){0.f, 0.f, 0.f, 0.f};
        c1b[nt] = (f32x4){0.f, 0.f, 0.f, 0.f};
      }
#pragma unroll
      for (int nt = 0; nt < 4; ++nt) {
        c1a[nt] = __builtin_amdgcn_mfma_f32_16x16x32_bf16(a00, bfrag[nt][0],
                                                          c1a[nt], 0, 0, 0);
        c1a[nt] = __builtin_amdgcn_mfma_f32_16x16x32_bf16(a01, bfrag[nt][1],
                                                          c1a[nt], 0, 0, 0);
        c1b[nt] = __builtin_amdgcn_mfma_f32_16x16x32_bf16(a10, bfrag[nt][0],
                                                          c1b[nt], 0, 0, 0);
        c1b[nt] = __builtin_amdgcn_mfma_f32_16x16x32_bf16(a11, bfrag[nt][1],
                                                          c1b[nt], 0, 0, 0);
      }

      // stage C1 as bf16: [n:64][m:32], 16B-slot XOR swizzle (slot ^= n&3)
#pragma unroll
      for (int nt = 0; nt < 4; ++nt) {
        const int n = nt * 16 + c;
        const int swz = n & 3;
        const int in0 = (q & 1) * 8;
        bf16x4 h0, h1;
#pragma unroll
        for (int r = 0; r < 4; ++r) {
          h0[r] = (__bf16)c1a[nt][r];
          h1[r] = (__bf16)c1b[nt][r];
        }
        *(bf16x4*)(stage + n * 64 + (((q >> 1) ^ swz) << 4) + in0) = h0;
        *(bf16x4*)(stage + n * 64 + (((2 + (q >> 1)) ^ swz) << 4) + in0) = h1;
      }

      // scatter: acc[rb] += P^T rows [16rb,16rb+16) (16x32) x C1 (32x64)
      bf16x8 pa[4];
#pragma unroll
      for (int rb = 0; rb < 4; ++rb)
        pa[rb] = *(const bf16x8*)(pmat + (rb * 16 + c) * 64 + ((q ^ (c & 3)) << 4));
#pragma unroll
      for (int nt = 0; nt < 4; ++nt) {
        const int n = nt * 16 + c;
        const bf16x8 bb = *(const bf16x8*)(stage + n * 64 + ((q ^ (n & 3)) << 4));
#pragma unroll
        for (int rb = 0; rb < 4; ++rb)
          acc[rb][nt] = __builtin_amdgcn_mfma_f32_16x16x32_bf16(pa[rb], bb,
                                                               acc[rb][nt], 0, 0, 0);
      }

      // unmark (restore pmat to all-zero for the next tile/bin)
      if (mol0 >= 0) {
        int m = c;
        *(__bf16*)(pmat + mol0 * 64 + (((m >> 3) ^ (mol0 & 3)) << 4) + (m & 7) * 2) =
            (__bf16)0.0f;
      }
      if (mol1 >= 0) {
        int m = 16 + c;
        *(__bf16*)(pmat + mol1 * 64 + (((m >> 3) ^ (mol1 & 3)) << 4) + (m & 7) * 2) =
            (__bf16)0.0f;
      }
    }
  }

  // ---- cross-wave reduce: 4 partial 64x64 f32 tiles -> wave 0, then store.
  __syncthreads();
  float* bufA = (float*)lds;              // 16 KB
  float* bufB = (float*)(lds + 16384);    // 16 KB

  // swizzled dword index: row = rb*16+q*4+r, col = nt*16+c; XOR spreads banks.
  auto REDST = [&](float* buf) {
#pragma unroll
    for (int rb = 0; rb < 4; ++rb)
#pragma unroll
      for (int nt = 0; nt < 4; ++nt)
#pragma unroll
        for (int r = 0; r < 4; ++r) {
          int row = rb * 16 + q * 4 + r;
          int col = (nt * 16 + c) ^ (q << 2) ^ ((q & 1) << 4);
          buf[row * 64 + col] = acc[rb][nt][r];
        }
  };
  auto REDADD = [&](const float* buf) {
#pragma unroll
    for (int rb = 0; rb < 4; ++rb)
#pragma unroll
      for (int nt = 0; nt < 4; ++nt)
#pragma unroll
        for (int r = 0; r < 4; ++r) {
          int row = rb * 16 + q * 4 + r;
          int col = (nt * 16 + c) ^ (q << 2) ^ ((q & 1) << 4);
          acc[rb][nt][r] += buf[row * 64 + col];
        }
  };

  if (wave == 1) REDST(bufA);
  if (wave == 3) REDST(bufB);
  __syncthreads();
  if (wave == 0) REDADD(bufA);
  if (wave == 2) REDADD(bufB);
  __syncthreads();
  if (wave == 2) REDST(bufA);
  __syncthreads();
  if (wave == 0) {
    REDADD(bufA);
    float bv[4];
#pragma unroll
    for (int nt = 0; nt < 4; ++nt) bv[nt] = bias[nt * 16 + c];
#pragma unroll
    for (int rb = 0; rb < 4; ++rb)
#pragma unroll
      for (int r = 0; r < 4; ++r) {
        const int row = b * RPB + rb * 16 + q * 4 + r;
        if (row < N_POINTS) {
#pragma unroll
          for (int nt = 0; nt < 4; ++nt)
            out[row * CCH + nt * 16 + c] = acc[rb][nt][r] + bv[nt];
        }
      }
  }
}

// ============================ fallback path (original) ============================

__global__ __launch_bounds__(256) void init_out_kernel(
    const float* __restrict__ bias, float* __restrict__ out) {
  int tid = blockIdx.x * blockDim.x + threadIdx.x;
  int c4 = tid & 15;
  float4 b = ((const float4*)bias)[c4];
  ((float4*)out)[tid] = b;
}

__global__ __launch_bounds__(256) void spconv_kernel(
    const float* __restrict__ input, const float* __restrict__ weight,
    const int* __restrict__ in_map, const int* __restrict__ out_map,
    float* __restrict__ out) {
  const int k = blockIdx.y;
  const int lane = threadIdx.x & 63;
  const int wave = threadIdx.x >> 6;
  const int col = lane & 15;
  const int quad = lane >> 4;

  const float* Wk = weight + k * (CCH * CCH);
  bf16x8 bfrag[4][2];
#pragma unroll
  for (int nt = 0; nt < 4; ++nt) {
    int co = nt * 16 + col;
#pragma unroll
    for (int s = 0; s < 2; ++s) {
      int ci0 = s * 32 + quad * 8;
      bf16x8 f;
#pragma unroll
      for (int j = 0; j < 8; ++j) f[j] = (__bf16)Wk[(ci0 + j) * CCH + co];
      bfrag[nt][s] = f;
    }
  }

  const int* im = in_map + k * PAIRS;
  const int* om = out_map + k * PAIRS;

  for (int tile = blockIdx.x * NWAVES + wave; tile < TILES_PER_K;
       tile += BX * NWAVES) {
    const int pbase = tile * 16;
    int rin = im[pbase + col];
    const float* arow = input + rin * CCH;
    bf16x8 afrag[2];
#pragma unroll
    for (int s = 0; s < 2; ++s) {
      const float4 x0 = *(const float4*)(arow + s * 32 + quad * 8);
      const float4 x1 = *(const float4*)(arow + s * 32 + quad * 8 + 4);
      bf16x8 f;
      f[0] = (__bf16)x0.x; f[1] = (__bf16)x0.y;
      f[2] = (__bf16)x0.z; f[3] = (__bf16)x0.w;
      f[4] = (__bf16)x1.x; f[5] = (__bf16)x1.y;
      f[6] = (__bf16)x1.z; f[7] = (__bf16)x1.w;
      afrag[s] = f;
    }

    f32x4 acc[4];
#pragma unroll
    for (int nt = 0; nt < 4; ++nt) acc[nt] = (f32x4){0.f, 0.f, 0.f, 0.f};
#pragma unroll
    for (int nt = 0; nt < 4; ++nt) {
      acc[nt] = __builtin_amdgcn_mfma_f32_16x16x32_bf16(afrag[0], bfrag[nt][0],
                                                        acc[nt], 0, 0, 0);
      acc[nt] = __builtin_amdgcn_mfma_f32_16x16x32_bf16(afrag[1], bfrag[nt][1],
                                                        acc[nt], 0, 0, 0);
    }

    int orow[4];
#pragma unroll
    for (int r = 0; r < 4; ++r) orow[r] = om[pbase + quad * 4 + r];
#pragma unroll
    for (int r = 0; r < 4; ++r) {
      float* op = out + orow[r] * CCH + col;
#pragma unroll
      for (int nt = 0; nt < 4; ++nt) atomicAdd(op + nt * 16, acc[nt][r]);
    }
  }
}

// ============================ launch ============================

extern "C" void kernel_launch(void* const* d_in, const int* in_sizes, int n_in,
                              void* d_out, int out_size, void* d_ws,
                              size_t ws_size, hipStream_t stream) {
  const float* input = (const float*)d_in[0];
  const float* weight = (const float*)d_in[1];
  const float* bias = (const float*)d_in[2];
  const int* in_map = (const int*)d_in[3];
  const int* out_map = (const int*)d_in[4];
  float* out = (float*)d_out;

  if (d_ws != nullptr && ws_size >= (size_t)WS_NEED) {
    unsigned char* ws = (unsigned char*)d_ws;
    hipMemsetAsync(ws + WS_CNT, 0, NBINS * 4, stream);
    prep_fill_kernel<<<PREP_BLKS + FILL_BLKS, 256, 0, stream>>>(
        input, weight, in_map, out_map, ws);
    spconv_main_kernel<<<NBUCKETS, 256, 0, stream>>>(bias, ws, out);
  } else {
    init_out_kernel<<<(N_POINTS * 16) / 256, 256, 0, stream>>>(bias, out);
    dim3 grid(BX, K_VOL);
    spconv_kernel<<<grid, 256, 0, stream>>>(input, weight, in_map, out_map, out);
  }
}